// Round 10
// baseline (126.882 us; speedup 1.0000x reference)
//
#include <hip/hip_runtime.h>
#include <hip/hip_bf16.h>

typedef __attribute__((ext_vector_type(8))) short short8;
typedef __attribute__((ext_vector_type(4))) float f32x4;
typedef unsigned short ushort_t;
typedef unsigned int uint32;

#define T_DIM   336
#define N_NODES 325
#define O_DIM   96
#define BD      384      // rows per node-group (B*D)
#define ND      975      // N*D
#define XB      327600   // T_DIM * ND
#define KT      96       // K per step
#define NSTEP   4        // K padded to 384
#define MT      96       // rows per workgroup (fits A + 2xB in <64KB LDS)
#define AST     104      // Atile stride (ushorts), mult of 8 -> 16B-aligned b128
#define BST     104      // Btile stride (ushorts)
#define BSEG    10240    // Bpack block stride in ushorts (layout from wprep)
#define BLDS    9984     // ushorts actually used per B tile = 96*104
#define WTO     32256    // 336*96
#define WP_T    120      // staged Wd rows per (nn,s): [t0-12, t0+108)

static __device__ __forceinline__ uint32 pk2bf(float a, float b) {
    union { __hip_bfloat16 h; ushort_t u; } x, y;
    x.h = __float2bfloat16(a); y.h = __float2bfloat16(b);
    return ((uint32)y.u << 16) | x.u;
}
static __device__ __forceinline__ ushort_t f2bf(float f) {
    union { __hip_bfloat16 h; ushort_t u; } cv;
    cv.h = __float2bfloat16(f);
    return cv.u;
}
static __device__ __forceinline__ float bf2f(ushort_t u) {
    union { ushort_t u; __hip_bfloat16 h; } cv;
    cv.u = u;
    return __bfloat162float(cv.h);
}

static __device__ __forceinline__ void gload_lds16(const void* g, void* l) {
    __builtin_amdgcn_global_load_lds(
        (const __attribute__((address_space(1))) void*)g,
        (__attribute__((address_space(3))) void*)l, 16, 0, 0);
}

// ---------------------------------------------------------------------------
// Kernel 1 (exact round-9 version): fold moving-average into weights.
// ---------------------------------------------------------------------------
__global__ __launch_bounds__(576, 7)
void dlinear_wprep(const float* __restrict__ Ws, const float* __restrict__ bs,
                   const float* __restrict__ Wt, const float* __restrict__ bt,
                   ushort_t* __restrict__ Bpack, float* __restrict__ biasArr)
{
    __shared__ ushort_t Wdl[WP_T][O_DIM];    // 23,040 B
    __shared__ ushort_t Bout[O_DIM * BST];   // 19,968 B, layout == Bpack block

    const int nn  = blockIdx.x;
    const int s   = blockIdx.y;
    const int tid = threadIdx.x;
    const int t0  = s * KT;

    const float* wsn = Ws + (size_t)nn * WTO;
    const float* wtn = Wt + (size_t)nn * WTO;

    {
        const int o   = tid % O_DIM;
        const int tA  = tid / O_DIM;
        #pragma unroll
        for (int it = 0; it < 20; ++it) {
            int t  = tA + it * 6;
            int tg = t0 - 12 + t;
            float v = 0.f;
            if (tg >= 0 && tg < T_DIM) v = wtn[tg*O_DIM + o] - wsn[tg*O_DIM + o];
            Wdl[t][o] = f2bf(v);
        }
    }
    if (s == 0 && tid < O_DIM)
        biasArr[nn*O_DIM + tid] = bs[nn*O_DIM + tid] + bt[nn*O_DIM + tid];
    __syncthreads();

    const int kc = tid / O_DIM;            // 0..5 (16 k's each)
    const int o  = tid - kc*O_DIM;
    const int k0 = kc * 16;

    float wsv[16];
    #pragma unroll
    for (int j = 0; j < 16; ++j) {
        int vv = t0 + k0 + j;
        wsv[j] = (vv < T_DIM) ? wsn[vv*O_DIM + o] : 0.f;
    }

    float S = 0.f;
    #pragma unroll
    for (int j = 0; j < 25; ++j) S += bf2f(Wdl[k0 + j][o]);

    uint32* bo32 = (uint32*)(Bout + o * BST);
    float prev = 0.f;
    #pragma unroll
    for (int j = 0; j < 16; ++j) {
        const int k = k0 + j;
        const int v = t0 + k;
        float val = 0.f;
        if (v < T_DIM) {
            float V = S;
            if (v == 0) {
                V = 0.f;
                #pragma unroll
                for (int t = 0; t <= 12; ++t) V += (float)(13 - t) * bf2f(Wdl[12 + t][o]);
            } else if (v == T_DIM - 1) {
                V = 0.f;
                #pragma unroll
                for (int t = 0; t <= 12; ++t) V += (float)(t + 1) * bf2f(Wdl[47 + t][o]);
            }
            val = wsv[j] + V * (1.0f/25.0f);
        }
        if (j & 1) bo32[k >> 1] = pk2bf(prev, val); else prev = val;
        if (j < 15) S += bf2f(Wdl[k + 25][o]) - bf2f(Wdl[k][o]);
    }
    __syncthreads();

    {
        const uint32* src = (const uint32*)Bout;
        uint32* dst = (uint32*)(Bpack + (size_t)(nn*4 + s) * BSEG);
        for (int d = tid; d < (O_DIM*BST)/2; d += 576)
            dst[d] = src[d];
    }
}

// ---------------------------------------------------------------------------
// Kernel 2 (v3): bf16 GEMM, all-x-upfront.
// All 96 x-loads per thread issued in the prologue (pinned by sched_barrier);
// the FIRST __syncthreads drains them as one full-MLP burst. Steps 1-3 pack
// from registers with zero load wait. B double-buffered via global_load_lds
// (B2/B3 issued mid-loop, drained by the existing syncs). MT=96, 384 thr,
// 6 waves (3M x 2N), LDS 59.9 KB -> 2 blocks/CU.
// ---------------------------------------------------------------------------
__global__ __launch_bounds__(384, 3)
void dlinear_gemm(const float* __restrict__ x,
                  const ushort_t* __restrict__ Bpack,
                  const float* __restrict__ biasArr,
                  float* __restrict__ Cws)
{
    __shared__ ushort_t Atile[MT][AST];    // 19,968 B
    __shared__ ushort_t Btile[2][BLDS];    // 39,936 B

    const int tid = threadIdx.x;
    const int bid = blockIdx.x;
    const int nn  = bid >> 2;
    const int mt  = bid & 3;
    const int r_base = nn * BD + mt * MT;

    const int m   = tid % MT;
    const int tb  = (tid / MT) * 24;          // 4 t-groups of 24
    const int r   = r_base + m;
    const int bI  = r / ND;
    const int rem = r - bI * ND;
    const float* xp = x + (size_t)bI * XB + rem;   // + t*ND

    const ushort_t* bsrc = Bpack + (size_t)nn * (4*BSEG);

    const int wave = tid >> 6;
    const int lane = tid & 63;
    const int wm = wave % 3;                  // 3 waves over M (32 rows each)
    const int wn = wave / 3;                  // 2 waves over O (48 cols each)
    const int a_row0 = wm*32 + (lane & 15);
    const int b_col0 = wn*48 + (lane & 15);
    const int ksub   = (lane >> 4) * 8;

    f32x4 acc[2][3];
    #pragma unroll
    for (int i = 0; i < 2; ++i)
        #pragma unroll
        for (int j = 0; j < 3; ++j)
            acc[i][j] = (f32x4){0.f, 0.f, 0.f, 0.f};

    // ---- prologue: B0/B1 DMA, then ALL x loads (4 steps x 24), pinned.
    {
        #pragma unroll
        for (int i = 0; i < 3; ++i)
            gload_lds16(bsrc + (size_t)(tid + 384*i)*8, &Btile[0][(tid + 384*i)*8]);
        if (tid < 96)
            gload_lds16(bsrc + (size_t)(tid + 1152)*8, &Btile[0][(tid + 1152)*8]);
        const ushort_t* b1 = bsrc + BSEG;
        #pragma unroll
        for (int i = 0; i < 3; ++i)
            gload_lds16(b1 + (size_t)(tid + 384*i)*8, &Btile[1][(tid + 384*i)*8]);
        if (tid < 96)
            gload_lds16(b1 + (size_t)(tid + 1152)*8, &Btile[1][(tid + 1152)*8]);
    }
    float v0[24], v1[24], v2[24], v3[24];
    #pragma unroll
    for (int u = 0; u < 24; ++u)
        v0[u] = __builtin_nontemporal_load(&xp[(tb + u) * ND]);
    #pragma unroll
    for (int u = 0; u < 24; ++u)
        v1[u] = __builtin_nontemporal_load(&xp[(96 + tb + u) * ND]);
    #pragma unroll
    for (int u = 0; u < 24; ++u)
        v2[u] = __builtin_nontemporal_load(&xp[(192 + tb + u) * ND]);
    #pragma unroll
    for (int u = 0; u < 24; ++u) {
        int t  = 288 + tb + u;
        int tc = t < T_DIM ? t : (T_DIM-1);   // K-pad: garbage x * 0-weight
        v3[u] = __builtin_nontemporal_load(&xp[tc * ND]);
    }
    __builtin_amdgcn_sched_barrier(0);        // pin issue point of all loads

#define PACK_A(VARR)                                                      \
    {                                                                     \
        uint32 p[12];                                                     \
        _Pragma("unroll")                                                 \
        for (int u = 0; u < 12; ++u) p[u] = pk2bf(VARR[2*u], VARR[2*u+1]);\
        uint32* arow = (uint32*)&Atile[m][tb];                            \
        *(uint4*)&arow[0] = make_uint4(p[0], p[1], p[2],  p[3]);          \
        *(uint4*)&arow[4] = make_uint4(p[4], p[5], p[6],  p[7]);          \
        *(uint4*)&arow[8] = make_uint4(p[8], p[9], p[10], p[11]);         \
    }

    PACK_A(v0);
    __syncthreads();   // ONE full-MLP drain of all x + B0 + B1

    #pragma unroll
    for (int s = 0; s < NSTEP; ++s) {
        // ---- MFMA: K=96, 3 chunks of 32, from Atile and Btile[s&1]
        #pragma unroll
        for (int kc = 0; kc < 3; ++kc) {
            const int k = kc*32 + ksub;
            short8 a0 = *(const short8*)&Atile[a_row0     ][k];
            short8 a1 = *(const short8*)&Atile[a_row0 + 16][k];
            short8 b0 = *(const short8*)&Btile[s & 1][(b_col0     )*BST + k];
            short8 b1 = *(const short8*)&Btile[s & 1][(b_col0 + 16)*BST + k];
            short8 b2 = *(const short8*)&Btile[s & 1][(b_col0 + 32)*BST + k];
            acc[0][0] = __builtin_amdgcn_mfma_f32_16x16x32_bf16(a0, b0, acc[0][0], 0, 0, 0);
            acc[1][0] = __builtin_amdgcn_mfma_f32_16x16x32_bf16(a1, b0, acc[1][0], 0, 0, 0);
            acc[0][1] = __builtin_amdgcn_mfma_f32_16x16x32_bf16(a0, b1, acc[0][1], 0, 0, 0);
            acc[1][1] = __builtin_amdgcn_mfma_f32_16x16x32_bf16(a1, b1, acc[1][1], 0, 0, 0);
            acc[0][2] = __builtin_amdgcn_mfma_f32_16x16x32_bf16(a0, b2, acc[0][2], 0, 0, 0);
            acc[1][2] = __builtin_amdgcn_mfma_f32_16x16x32_bf16(a1, b2, acc[1][2], 0, 0, 0);
        }

        if (s < NSTEP - 1) {
            __syncthreads();   // Atile and Btile[s&1] free for reuse

            if (s < 2) {       // B_{s+2} DMA into the buffer MFMA_s just read
                const ushort_t* bn = bsrc + (size_t)(s + 2) * BSEG;
                ushort_t* bl = &Btile[s & 1][0];
                #pragma unroll
                for (int i = 0; i < 3; ++i)
                    gload_lds16(bn + (size_t)(tid + 384*i)*8, bl + (tid + 384*i)*8);
                if (tid < 96)
                    gload_lds16(bn + (size_t)(tid + 1152)*8, bl + (tid + 1152)*8);
            }
            if (s == 0)      PACK_A(v1)
            else if (s == 1) PACK_A(v2)
            else             PACK_A(v3)
            __syncthreads();   // A writes visible; B DMA drained
        }
    }
#undef PACK_A

    // ---- epilogue: C/D map col=lane&15, row=(lane>>4)*4+j
    float* Cbase = Cws + (size_t)r_base * O_DIM;
    const float* bfp = biasArr + nn * O_DIM;
    const int rsub = (lane >> 4) * 4;
    #pragma unroll
    for (int fm = 0; fm < 2; ++fm) {
        #pragma unroll
        for (int fn = 0; fn < 3; ++fn) {
            const int col = b_col0 + fn*16;
            const float bv = bfp[col];
            #pragma unroll
            for (int j = 0; j < 4; ++j) {
                const int rowm = wm*32 + fm*16 + rsub + j;
                Cbase[rowm*O_DIM + col] = acc[fm][fn][j] + bv;
            }
        }
    }
}

// ---------------------------------------------------------------------------
// Kernel 3: layout fixup (exact round-3/9 version).
// ---------------------------------------------------------------------------
__global__ __launch_bounds__(256)
void dlinear_out(const float* __restrict__ Cws, float* __restrict__ out)
{
    __shared__ float tile[65][97];
    const int m   = blockIdx.x;           // 0..383
    const int nn0 = blockIdx.y * 65;      // 325 = 5*65
    const int tid = threadIdx.x;

    for (int idx = tid; idx < 65*O_DIM; idx += 256) {
        int nni = idx / O_DIM;
        int o   = idx - nni*O_DIM;
        tile[nni][o] = Cws[(size_t)((nn0 + nni)*BD + m)*O_DIM + o];
    }
    __syncthreads();
    const int b = m / 3;
    const int g = m - b*3;
    float* obase = out + (size_t)b*93600 + g*N_NODES + nn0;
    for (int idx = tid; idx < 65*O_DIM; idx += 256) {
        int o   = idx / 65;
        int nni = idx - o*65;
        obase[o*ND + nni] = tile[nni][o];
    }
}

extern "C" void kernel_launch(void* const* d_in, const int* in_sizes, int n_in,
                              void* d_out, int out_size, void* d_ws, size_t ws_size,
                              hipStream_t stream)
{
    const float* x  = (const float*)d_in[0];
    const float* Ws = (const float*)d_in[1];
    const float* bs = (const float*)d_in[2];
    const float* Wt = (const float*)d_in[3];
    const float* bt = (const float*)d_in[4];
    float* out = (float*)d_out;
    float* Cws = (float*)d_ws;                     // 124800*96*4 = 47.9 MB

    // Packed bf16 weights + bias live in the d_out tail (26.6 MB + 122 KB of
    // 45.7 MB). Final transpose overwrites all of d_out; Bpack regenerated
    // every call => deterministic replays.
    ushort_t* Bpack  = (ushort_t*)d_out;
    float*    biasAr = (float*)d_out + 6656000;    // = 325*4*10240/2

    dlinear_wprep<<<dim3(N_NODES, 4), dim3(576), 0, stream>>>(Ws, bs, Wt, bt, Bpack, biasAr);
    dlinear_gemm <<<dim3(1300),       dim3(384), 0, stream>>>(x, Bpack, biasAr, Cws);
    dlinear_out  <<<dim3(384, 5),     dim3(256), 0, stream>>>(Cws, out);
}